// Round 1
// baseline (181.148 us; speedup 1.0000x reference)
//
#include <hip/hip_runtime.h>
#include <math.h>

// Problem geometry (fixed by reference): x[64, 256, 32, 32] fp32.
#define N_DIM   64
#define C_DIM   256
#define HW_DIM  1024                 // 32*32
#define M_DIM   (N_DIM * HW_DIM)    // 65536 values per channel
#define SLABS   (N_DIM * C_DIM)     // 16384 slabs of 1024 contiguous floats
#define F4_PER_SLAB 256             // 1024 floats / 4
#define TOTAL_F4 (SLABS * F4_PER_SLAB)  // 4194304
#define K_TOP   100
#define EPS_F   1e-7f

// ---------------------------------------------------------------------------
// Kernel 1: per-slab (n,c) partial sums in double. 16384 blocks x 256 threads,
// one float4 per thread. Deterministic, warms L3 with x.
// ---------------------------------------------------------------------------
__global__ __launch_bounds__(256) void slab_sum_kernel(
    const float4* __restrict__ x4, double* __restrict__ slab_sums)
{
    const int slab = blockIdx.x;
    float4 v = x4[(size_t)slab * F4_PER_SLAB + threadIdx.x];
    double s = (double)v.x + (double)v.y + (double)v.z + (double)v.w;
    #pragma unroll
    for (int off = 32; off > 0; off >>= 1) s += __shfl_down(s, off, 64);
    __shared__ double wsum[4];
    const int lane = threadIdx.x & 63, wv = threadIdx.x >> 6;
    if (lane == 0) wsum[wv] = s;
    __syncthreads();
    if (threadIdx.x == 0)
        slab_sums[slab] = wsum[0] + wsum[1] + wsum[2] + wsum[3];
}

// ---------------------------------------------------------------------------
// Kernel 2: per-channel stats. One block (512 threads) per channel.
// Phase 0: mean from slab sums.
// Phases A/B/C: exact radix-select of v_K (K-th largest |x - mean|) via
//   12+12+8-bit LDS histograms over the fp32 bit pattern (positive floats are
//   monotone as u32).
// Phase D: sum of values strictly above v_K; top-K sum = sum_gt + m*v_K.
// Emits alpha[c] = scale*weight[c], beta[c] = bias[c] - mean*alpha[c].
// ---------------------------------------------------------------------------
#define STATS_THREADS 512

__device__ __forceinline__ double block_reduce_double(double v, double* dred, int tid)
{
    #pragma unroll
    for (int off = 32; off > 0; off >>= 1) v += __shfl_down(v, off, 64);
    const int lane = tid & 63, wv = tid >> 6;
    __syncthreads();
    if (lane == 0) dred[wv] = v;
    __syncthreads();
    double r = 0.0;
    if (tid == 0) {
        #pragma unroll
        for (int i = 0; i < STATS_THREADS / 64; ++i) r += dred[i];
    }
    return r;   // valid on tid 0 only
}

// Select, within hist[0..nbins), the bin containing the Krem-th largest value
// (bins ascending in value). Writes selected bin and count strictly above it
// (within this histogram) to LDS outputs. psum/ssum are scratch [512].
__device__ __forceinline__ void select_bin(
    const unsigned int* hist, int nbins, unsigned int Krem,
    unsigned int* psum, unsigned int* ssum,
    unsigned int* out_bin, unsigned int* out_cntgt, int tid)
{
    const int bpt = (nbins + STATS_THREADS - 1) / STATS_THREADS;
    const int lo = tid * bpt;
    const int hi = min(nbins, lo + bpt);
    unsigned int s = 0;
    for (int b = lo; b < hi; ++b) s += hist[b];
    psum[tid] = s;
    ssum[tid] = s;
    __syncthreads();
    // Hillis-Steele suffix sums: ssum[t] = sum_{t' >= t} psum[t']
    for (int off = 1; off < STATS_THREADS; off <<= 1) {
        unsigned int add = (tid + off < STATS_THREADS) ? ssum[tid + off] : 0u;
        __syncthreads();
        ssum[tid] += add;
        __syncthreads();
    }
    const unsigned int S_excl = ssum[tid] - psum[tid];   // strictly-above-my-range count
    if (S_excl < Krem && S_excl + psum[tid] >= Krem) {
        unsigned int cum = S_excl;
        for (int b = hi - 1; b >= lo; --b) {
            unsigned int h = hist[b];
            if (cum + h >= Krem) { *out_bin = (unsigned int)b; *out_cntgt = cum; break; }
            cum += h;
        }
    }
    __syncthreads();
}

__global__ __launch_bounds__(STATS_THREADS) void stats_kernel(
    const float4* __restrict__ x4, const double* __restrict__ slab_sums,
    const float* __restrict__ weight, const float* __restrict__ bias,
    float* __restrict__ alpha, float* __restrict__ beta, float cconst)
{
    const int c = blockIdx.x;
    const int tid = threadIdx.x;

    __shared__ unsigned int hist[4096];
    __shared__ unsigned int psum[STATS_THREADS];
    __shared__ unsigned int ssum[STATS_THREADS];
    __shared__ double dred[STATS_THREADS / 64];
    __shared__ float s_mean;
    __shared__ unsigned int s_bin, s_cnt;

    // ---- Phase 0: mean ----
    double msum = 0.0;
    for (int n = tid; n < N_DIM; n += STATS_THREADS) msum += slab_sums[n * C_DIM + c];
    double tot = block_reduce_double(msum, dred, tid);
    if (tid == 0) s_mean = (float)(tot / (double)M_DIM);
    __syncthreads();
    const float mean = s_mean;

    unsigned int cnt_gt_total = 0;

    // ---- Phase A: level-1 histogram (top 12 bits) ----
    for (int i = tid; i < 4096; i += STATS_THREADS) hist[i] = 0u;
    __syncthreads();
    for (int g = tid; g < M_DIM / 4; g += STATS_THREADS) {
        const int n = g >> 8, off = g & 255;
        float4 v = x4[((size_t)(n * C_DIM + c)) * F4_PER_SLAB + off];
        float vals[4] = {v.x, v.y, v.z, v.w};
        #pragma unroll
        for (int j = 0; j < 4; ++j) {
            unsigned int u = __float_as_uint(fabsf(vals[j] - mean));
            atomicAdd(&hist[u >> 20], 1u);
        }
    }
    __syncthreads();
    select_bin(hist, 4096, K_TOP, psum, ssum, &s_bin, &s_cnt, tid);
    const unsigned int b1 = s_bin;
    cnt_gt_total += s_cnt;
    const unsigned int K2 = K_TOP - s_cnt;
    __syncthreads();

    // ---- Phase B: level-2 histogram (middle 12 bits) among top12 == b1 ----
    for (int i = tid; i < 4096; i += STATS_THREADS) hist[i] = 0u;
    __syncthreads();
    for (int g = tid; g < M_DIM / 4; g += STATS_THREADS) {
        const int n = g >> 8, off = g & 255;
        float4 v = x4[((size_t)(n * C_DIM + c)) * F4_PER_SLAB + off];
        float vals[4] = {v.x, v.y, v.z, v.w};
        #pragma unroll
        for (int j = 0; j < 4; ++j) {
            unsigned int u = __float_as_uint(fabsf(vals[j] - mean));
            if ((u >> 20) == b1) atomicAdd(&hist[(u >> 8) & 0xFFFu], 1u);
        }
    }
    __syncthreads();
    select_bin(hist, 4096, K2, psum, ssum, &s_bin, &s_cnt, tid);
    const unsigned int b2 = s_bin;
    cnt_gt_total += s_cnt;
    const unsigned int K3 = K2 - s_cnt;
    const unsigned int pfx24 = (b1 << 12) | b2;
    __syncthreads();

    // ---- Phase C: level-3 histogram (low 8 bits) among top24 == pfx24 ----
    for (int i = tid; i < 4096; i += STATS_THREADS) hist[i] = 0u;
    __syncthreads();
    for (int g = tid; g < M_DIM / 4; g += STATS_THREADS) {
        const int n = g >> 8, off = g & 255;
        float4 v = x4[((size_t)(n * C_DIM + c)) * F4_PER_SLAB + off];
        float vals[4] = {v.x, v.y, v.z, v.w};
        #pragma unroll
        for (int j = 0; j < 4; ++j) {
            unsigned int u = __float_as_uint(fabsf(vals[j] - mean));
            if ((u >> 8) == pfx24) atomicAdd(&hist[u & 0xFFu], 1u);
        }
    }
    __syncthreads();
    select_bin(hist, 256, K3, psum, ssum, &s_bin, &s_cnt, tid);
    cnt_gt_total += s_cnt;
    const unsigned int vk_bits = (pfx24 << 8) | s_bin;
    __syncthreads();

    // ---- Phase D: sum of values strictly greater than v_K ----
    double sgt = 0.0;
    for (int g = tid; g < M_DIM / 4; g += STATS_THREADS) {
        const int n = g >> 8, off = g & 255;
        float4 v = x4[((size_t)(n * C_DIM + c)) * F4_PER_SLAB + off];
        float vals[4] = {v.x, v.y, v.z, v.w};
        #pragma unroll
        for (int j = 0; j < 4; ++j) {
            float a = fabsf(vals[j] - mean);
            if (__float_as_uint(a) > vk_bits) sgt += (double)a;
        }
    }
    double sum_gt = block_reduce_double(sgt, dred, tid);

    if (tid == 0) {
        const float vK = __uint_as_float(vk_bits);
        const double top_sum = sum_gt + (double)(K_TOP - cnt_gt_total) * (double)vK;
        const float mean_topk = (float)(top_sum / (double)K_TOP) * cconst;
        const float scale = 1.0f / (mean_topk + EPS_F);
        const float a = scale * weight[c];
        alpha[c] = a;
        beta[c]  = bias[c] - mean * a;
    }
}

// ---------------------------------------------------------------------------
// Kernel 3: out = x * alpha[c] + beta[c], float4 streaming.
// Block of 256 threads covers exactly one slab per sweep -> uniform channel.
// ---------------------------------------------------------------------------
__global__ __launch_bounds__(256) void apply_kernel(
    const float4* __restrict__ x4, const float* __restrict__ alpha,
    const float* __restrict__ beta, float4* __restrict__ out4)
{
    const size_t stride = (size_t)gridDim.x * blockDim.x;
    for (size_t i = (size_t)blockIdx.x * blockDim.x + threadIdx.x; i < (size_t)TOTAL_F4; i += stride) {
        const int cch = (int)((i >> 8) & (C_DIM - 1));
        const float a = alpha[cch];
        const float b = beta[cch];
        float4 v = x4[i];
        float4 o;
        o.x = fmaf(v.x, a, b);
        o.y = fmaf(v.y, a, b);
        o.z = fmaf(v.z, a, b);
        o.w = fmaf(v.w, a, b);
        out4[i] = o;
    }
}

// ---------------------------------------------------------------------------
extern "C" void kernel_launch(void* const* d_in, const int* in_sizes, int n_in,
                              void* d_out, int out_size, void* d_ws, size_t ws_size,
                              hipStream_t stream)
{
    const float* x = (const float*)d_in[0];
    const float* w = (const float*)d_in[1];
    const float* b = (const float*)d_in[2];
    float* out = (float*)d_out;

    double* slab_sums = (double*)d_ws;                       // 16384 doubles = 128 KiB
    float*  alpha     = (float*)((char*)d_ws + SLABS * sizeof(double));
    float*  beta      = alpha + C_DIM;

    const int M = in_sizes[0] / in_sizes[1];                 // 65536
    const double cst = 0.5 * (1.0 + sqrt(M_PI * log(4.0))) / sqrt(2.0 * log((double)M));

    slab_sum_kernel<<<SLABS, 256, 0, stream>>>((const float4*)x, slab_sums);
    stats_kernel<<<C_DIM, STATS_THREADS, 0, stream>>>(
        (const float4*)x, slab_sums, w, b, alpha, beta, (float)cst);
    apply_kernel<<<4096, 256, 0, stream>>>((const float4*)x, alpha, beta, (float4*)out);
}

// Round 2
// 144.591 us; speedup vs baseline: 1.2528x; 1.2528x over previous
//
#include <hip/hip_runtime.h>
#include <math.h>

// Problem geometry (fixed by reference): x[64, 256, 32, 32] fp32.
#define N_DIM   64
#define C_DIM   256
#define M_DIM   65536               // values per channel = 64*32*32
#define SLABS   16384               // 64*256 slabs of 1024 contiguous floats
#define F4_PER_SLAB 256
#define K_TOP   100
#define EPS_F   1e-7f
#define THREADS 1024
#define CAP     8192                // LDS candidate buffer capacity

// ---------------------------------------------------------------------------
// Kernel 1: per-slab (n,c) sums. 4096 blocks x 256; each wave owns one slab.
// ---------------------------------------------------------------------------
__global__ __launch_bounds__(256) void slab_sum_kernel(
    const float4* __restrict__ x4, double* __restrict__ slab_sums)
{
    const int wv = threadIdx.x >> 6, lane = threadIdx.x & 63;
    const int slab = (blockIdx.x << 2) + wv;
    const float4* p = x4 + (size_t)slab * F4_PER_SLAB;
    double s = 0.0;
    #pragma unroll
    for (int i = 0; i < 4; ++i) {
        float4 v = p[lane + (i << 6)];
        s += (double)v.x + (double)v.y + (double)v.z + (double)v.w;
    }
    #pragma unroll
    for (int off = 32; off > 0; off >>= 1) s += __shfl_down(s, off, 64);
    if (lane == 0) slab_sums[slab] = s;
}

// ---------------------------------------------------------------------------
// Fused per-channel kernel: mean -> radix-select v_K -> topK sum -> apply.
// One block (1024 threads) per channel.
// ---------------------------------------------------------------------------
__device__ __forceinline__ double block_reduce_double(double v, double* dred, int tid)
{
    #pragma unroll
    for (int off = 32; off > 0; off >>= 1) v += __shfl_down(v, off, 64);
    const int lane = tid & 63, wv = tid >> 6;
    __syncthreads();
    if (lane == 0) dred[wv] = v;
    __syncthreads();
    double r = 0.0;
    if (tid == 0) {
        #pragma unroll
        for (int i = 0; i < THREADS / 64; ++i) r += dred[i];
    }
    return r;   // valid on tid 0 only
}

// Find, in hist[0..nbins) (bins ascending in value), the bin holding the
// Krem-th largest element; writes bin index and count strictly above it.
__device__ __forceinline__ void select_bin(
    const unsigned int* hist, int nbins, unsigned int Krem,
    unsigned int* psum, unsigned int* ssum,
    unsigned int* out_bin, unsigned int* out_cntgt, int tid)
{
    const int bpt = (nbins + THREADS - 1) / THREADS;
    const int lo = tid * bpt;
    const int hi = min(nbins, lo + bpt);
    unsigned int s = 0;
    for (int b = lo; b < hi; ++b) s += hist[b];
    psum[tid] = s;
    ssum[tid] = s;
    __syncthreads();
    for (int off = 1; off < THREADS; off <<= 1) {   // suffix sums
        unsigned int add = (tid + off < THREADS) ? ssum[tid + off] : 0u;
        __syncthreads();
        ssum[tid] += add;
        __syncthreads();
    }
    const unsigned int S_excl = ssum[tid] - psum[tid];
    if (S_excl < Krem && S_excl + psum[tid] >= Krem) {
        unsigned int cum = S_excl;
        for (int b = hi - 1; b >= lo; --b) {
            unsigned int h = hist[b];
            if (cum + h >= Krem) { *out_bin = (unsigned int)b; *out_cntgt = cum; break; }
            cum += h;
        }
    }
    __syncthreads();
}

#define CHAN_IDX(g) (((size_t)(((g) >> 8 << 8) | c) << 8) + ((g) & 255))
// note: n = g>>8, off = g&255, idx = ((n*C_DIM + c)*256 + off) with C_DIM=256

__global__ __launch_bounds__(THREADS) void fused_kernel(
    const float4* __restrict__ x4, const double* __restrict__ slab_sums,
    const float* __restrict__ weight, const float* __restrict__ bias,
    float4* __restrict__ out4, float cconst)
{
    const int c = blockIdx.x;
    const int tid = threadIdx.x;

    __shared__ unsigned int hist[4096];
    __shared__ unsigned int psum[THREADS];
    __shared__ unsigned int ssum[THREADS];
    __shared__ unsigned int cand[CAP];
    __shared__ double dred[THREADS / 64];
    __shared__ float s_mean;
    __shared__ unsigned int s_bin, s_cnt, s_ccnt;
    __shared__ float s_alpha, s_beta;

    // ---- mean from slab sums ----
    double msum = 0.0;
    for (int n = tid; n < N_DIM; n += THREADS) msum += slab_sums[n * C_DIM + c];
    double tot = block_reduce_double(msum, dred, tid);
    if (tid == 0) s_mean = (float)(tot / (double)M_DIM);
    __syncthreads();
    const float mean = s_mean;

    // ---- Pass A: 12-bit (exp + 4 mantissa) histogram of |x - mean| ----
    for (int i = tid; i < 4096; i += THREADS) hist[i] = 0u;
    __syncthreads();
    for (int g = tid; g < M_DIM / 4; g += THREADS) {
        float4 v = x4[CHAN_IDX(g)];
        float vals[4] = {v.x, v.y, v.z, v.w};
        #pragma unroll
        for (int j = 0; j < 4; ++j) {
            unsigned int u = __float_as_uint(fabsf(vals[j] - mean));
            atomicAdd(&hist[u >> 20], 1u);
        }
    }
    __syncthreads();
    select_bin(hist, 4096, K_TOP, psum, ssum, &s_bin, &s_cnt, tid);
    const unsigned int b1 = s_bin;
    const unsigned int n1 = s_cnt;               // count strictly above bin b1
    const unsigned int inb1 = hist[b1];
    const unsigned int K2 = K_TOP - n1;
    __syncthreads();

    unsigned int vk_bits;
    unsigned int cnt_gt_total = n1;
    double sum_gt;

    if (n1 + inb1 <= CAP) {
        // ---- Pass B: collect all candidates (top-12-bits >= b1) into LDS ----
        if (tid == 0) s_ccnt = 0u;
        __syncthreads();
        for (int g = tid; g < M_DIM / 4; g += THREADS) {
            float4 v = x4[CHAN_IDX(g)];
            float vals[4] = {v.x, v.y, v.z, v.w};
            #pragma unroll
            for (int j = 0; j < 4; ++j) {
                unsigned int u = __float_as_uint(fabsf(vals[j] - mean));
                if ((u >> 20) >= b1) { unsigned int p = atomicAdd(&s_ccnt, 1u); cand[p] = u; }
            }
        }
        __syncthreads();
        const unsigned int cnt = s_ccnt;

        // ---- level 2 select (bits [19:8]) within bin b1, from LDS ----
        for (int i = tid; i < 4096; i += THREADS) hist[i] = 0u;
        __syncthreads();
        for (unsigned int i = tid; i < cnt; i += THREADS) {
            unsigned int u = cand[i];
            if ((u >> 20) == b1) atomicAdd(&hist[(u >> 8) & 0xFFFu], 1u);
        }
        __syncthreads();
        select_bin(hist, 4096, K2, psum, ssum, &s_bin, &s_cnt, tid);
        const unsigned int b2 = s_bin;
        const unsigned int K3 = K2 - s_cnt;
        const unsigned int pfx24 = (b1 << 12) | b2;
        cnt_gt_total += s_cnt;
        __syncthreads();

        // ---- level 3 select (bits [7:0]), from LDS ----
        for (int i = tid; i < 256; i += THREADS) hist[i] = 0u;
        __syncthreads();
        for (unsigned int i = tid; i < cnt; i += THREADS) {
            unsigned int u = cand[i];
            if ((u >> 8) == pfx24) atomicAdd(&hist[u & 0xFFu], 1u);
        }
        __syncthreads();
        select_bin(hist, 256, K3, psum, ssum, &s_bin, &s_cnt, tid);
        cnt_gt_total += s_cnt;
        vk_bits = (pfx24 << 8) | s_bin;
        __syncthreads();

        // ---- sum of candidates strictly above v_K (exact, in LDS) ----
        double sgt = 0.0;
        for (unsigned int i = tid; i < cnt; i += THREADS) {
            unsigned int u = cand[i];
            if (u > vk_bits) sgt += (double)__uint_as_float(u);
        }
        sum_gt = block_reduce_double(sgt, dred, tid);
    } else {
        // ---- fallback: exact multi-pass refine from global (degenerate data) ----
        for (int i = tid; i < 4096; i += THREADS) hist[i] = 0u;
        __syncthreads();
        for (int g = tid; g < M_DIM / 4; g += THREADS) {
            float4 v = x4[CHAN_IDX(g)];
            float vals[4] = {v.x, v.y, v.z, v.w};
            #pragma unroll
            for (int j = 0; j < 4; ++j) {
                unsigned int u = __float_as_uint(fabsf(vals[j] - mean));
                if ((u >> 20) == b1) atomicAdd(&hist[(u >> 8) & 0xFFFu], 1u);
            }
        }
        __syncthreads();
        select_bin(hist, 4096, K2, psum, ssum, &s_bin, &s_cnt, tid);
        const unsigned int b2 = s_bin;
        const unsigned int K3 = K2 - s_cnt;
        const unsigned int pfx24 = (b1 << 12) | b2;
        cnt_gt_total += s_cnt;
        __syncthreads();

        for (int i = tid; i < 256; i += THREADS) hist[i] = 0u;
        __syncthreads();
        for (int g = tid; g < M_DIM / 4; g += THREADS) {
            float4 v = x4[CHAN_IDX(g)];
            float vals[4] = {v.x, v.y, v.z, v.w};
            #pragma unroll
            for (int j = 0; j < 4; ++j) {
                unsigned int u = __float_as_uint(fabsf(vals[j] - mean));
                if ((u >> 8) == pfx24) atomicAdd(&hist[u & 0xFFu], 1u);
            }
        }
        __syncthreads();
        select_bin(hist, 256, K3, psum, ssum, &s_bin, &s_cnt, tid);
        cnt_gt_total += s_cnt;
        vk_bits = (pfx24 << 8) | s_bin;
        __syncthreads();

        double sgt = 0.0;
        for (int g = tid; g < M_DIM / 4; g += THREADS) {
            float4 v = x4[CHAN_IDX(g)];
            float vals[4] = {v.x, v.y, v.z, v.w};
            #pragma unroll
            for (int j = 0; j < 4; ++j) {
                float a = fabsf(vals[j] - mean);
                if (__float_as_uint(a) > vk_bits) sgt += (double)a;
            }
        }
        sum_gt = block_reduce_double(sgt, dred, tid);
    }

    // ---- alpha/beta ----
    if (tid == 0) {
        const float vK = __uint_as_float(vk_bits);
        const double top_sum = sum_gt + (double)(K_TOP - cnt_gt_total) * (double)vK;
        const float mean_topk = (float)(top_sum / (double)K_TOP) * cconst;
        const float scale = 1.0f / (mean_topk + EPS_F);
        const float a = scale * weight[c];
        s_alpha = a;
        s_beta  = bias[c] - mean * a;
    }
    __syncthreads();

    // ---- fused apply: out = x*alpha + beta over this channel ----
    const float a = s_alpha, b = s_beta;
    for (int g = tid; g < M_DIM / 4; g += THREADS) {
        const size_t idx = CHAN_IDX(g);
        float4 v = x4[idx];
        float4 o;
        o.x = fmaf(v.x, a, b);
        o.y = fmaf(v.y, a, b);
        o.z = fmaf(v.z, a, b);
        o.w = fmaf(v.w, a, b);
        out4[idx] = o;
    }
}

// ---------------------------------------------------------------------------
extern "C" void kernel_launch(void* const* d_in, const int* in_sizes, int n_in,
                              void* d_out, int out_size, void* d_ws, size_t ws_size,
                              hipStream_t stream)
{
    const float* x = (const float*)d_in[0];
    const float* w = (const float*)d_in[1];
    const float* b = (const float*)d_in[2];
    float* out = (float*)d_out;

    double* slab_sums = (double*)d_ws;   // 16384 doubles = 128 KiB

    const int M = in_sizes[0] / in_sizes[1];   // 65536
    const double cst = 0.5 * (1.0 + sqrt(M_PI * log(4.0))) / sqrt(2.0 * log((double)M));

    slab_sum_kernel<<<SLABS / 4, 256, 0, stream>>>((const float4*)x, slab_sums);
    fused_kernel<<<C_DIM, THREADS, 0, stream>>>(
        (const float4*)x, slab_sums, w, b, (float4*)out, (float)cst);
}